// Round 1
// baseline (1236.235 us; speedup 1.0000x reference)
//
#include <hip/hip_runtime.h>
#include <hip/hip_bf16.h>

#define T_TOK 4096
#define DMODEL 1024
#define DFF 4096
#define NEXP 8
#define ROWS_TOT 8192      // T_TOK * TOPK, fixed
#define ROWS_PAD 8320      // + 128 pad rows for tile overrun

typedef __bf16 bf16x8 __attribute__((ext_vector_type(8)));
typedef float f32x4 __attribute__((ext_vector_type(4)));
typedef unsigned short u16;

__device__ __forceinline__ u16 f2bf(float f) {
    __hip_bfloat16 b = __float2bfloat16(f);
    return __builtin_bit_cast(u16, b);
}

// ---------------- router: logits, softmax-top2 gates, expert histogram ----------
__global__ void router_kernel(const float* __restrict__ x, const float* __restrict__ Wr,
                              const float* __restrict__ br, int* __restrict__ top_idx,
                              float* __restrict__ gates, int* __restrict__ counts) {
    const int t = blockIdx.x;
    const int lane = threadIdx.x;
    float part[8];
#pragma unroll
    for (int e = 0; e < 8; ++e) part[e] = 0.f;
#pragma unroll
    for (int j = 0; j < 4; ++j) {
        const int d0 = j * 256 + lane * 4;
        const float4 xv = *(const float4*)(x + (size_t)t * DMODEL + d0);
        const float xs[4] = {xv.x, xv.y, xv.z, xv.w};
#pragma unroll
        for (int i = 0; i < 4; ++i) {
            const float4 w0 = *(const float4*)(Wr + (d0 + i) * 8);
            const float4 w1 = *(const float4*)(Wr + (d0 + i) * 8 + 4);
            part[0] += xs[i] * w0.x; part[1] += xs[i] * w0.y;
            part[2] += xs[i] * w0.z; part[3] += xs[i] * w0.w;
            part[4] += xs[i] * w1.x; part[5] += xs[i] * w1.y;
            part[6] += xs[i] * w1.z; part[7] += xs[i] * w1.w;
        }
    }
#pragma unroll
    for (int m = 32; m > 0; m >>= 1)
#pragma unroll
        for (int e = 0; e < 8; ++e) part[e] += __shfl_xor(part[e], m, 64);
    if (lane == 0) {
        float l[8];
#pragma unroll
        for (int e = 0; e < 8; ++e) l[e] = part[e] + br[e];
        int i1 = 0;
#pragma unroll
        for (int e = 1; e < 8; ++e) if (l[e] > l[i1]) i1 = e;   // first-index tiebreak
        int i2 = (i1 == 0) ? 1 : 0;
#pragma unroll
        for (int e = 0; e < 8; ++e) if (e != i1 && l[e] > l[i2]) i2 = e;
        // gates = softmax over {l[i1], l[i2]} (== topk(softmax)/sum(topk))
        const float e2 = expf(l[i2] - l[i1]);
        const float inv = 1.f / (1.f + e2);
        top_idx[t * 2 + 0] = i1;  gates[t * 2 + 0] = inv;
        top_idx[t * 2 + 1] = i2;  gates[t * 2 + 1] = e2 * inv;
        atomicAdd(&counts[i1], 1);
        atomicAdd(&counts[i2], 1);
    }
}

// ---------------- exclusive scan over 8 counts -----------------------------------
__global__ void scan_kernel(const int* __restrict__ counts, int* __restrict__ offs,
                            int* __restrict__ cursor) {
    if (threadIdx.x == 0) {
        int s = 0;
        for (int e = 0; e < 8; ++e) { offs[e] = s; cursor[e] = s; s += counts[e]; }
        offs[8] = s;
    }
}

// ---------------- fill sorted row lists ------------------------------------------
__global__ void fill_kernel(const int* __restrict__ top_idx, const float* __restrict__ gates,
                            int* __restrict__ cursor, int* __restrict__ rowtoken,
                            float* __restrict__ rowgate) {
    const int t = blockIdx.x * 256 + threadIdx.x;
    if (t >= T_TOK) return;
#pragma unroll
    for (int k = 0; k < 2; ++k) {
        const int e = top_idx[t * 2 + k];
        const int p = atomicAdd(&cursor[e], 1);
        rowtoken[p] = t;
        rowgate[p] = gates[t * 2 + k];
    }
}

// ---------------- gather x rows (fp32 -> bf16) into sorted order -----------------
__global__ void gather_kernel(const float* __restrict__ x, const int* __restrict__ rowtoken,
                              u16* __restrict__ Xg) {
    const int p = blockIdx.x;
    const int t = rowtoken[p];
    const int d = threadIdx.x * 4;
    const float4 v = *(const float4*)(x + (size_t)t * DMODEL + d);
    ushort4 o;
    o.x = f2bf(v.x); o.y = f2bf(v.y); o.z = f2bf(v.z); o.w = f2bf(v.w);
    *(ushort4*)(Xg + (size_t)p * DMODEL + d) = o;
}

// ---------------- transpose + fp32->bf16 weight conversion -----------------------
// src [batch][R][C] f32 -> dst [batch][C][R] bf16
__global__ __launch_bounds__(256) void transpose_convert_kernel(
    const float* __restrict__ src, u16* __restrict__ dst, int R, int C) {
    __shared__ float tile[64][65];
    const size_t base = (size_t)blockIdx.z * R * C;
    const int r0 = blockIdx.y * 64, c0 = blockIdx.x * 64;
    const int tr = threadIdx.x >> 4;
    const int tc4 = (threadIdx.x & 15) * 4;
#pragma unroll
    for (int i = 0; i < 4; ++i) {
        const int r = tr + i * 16;
        const float4 v = *(const float4*)(src + base + (size_t)(r0 + r) * C + c0 + tc4);
        tile[r][tc4 + 0] = v.x; tile[r][tc4 + 1] = v.y;
        tile[r][tc4 + 2] = v.z; tile[r][tc4 + 3] = v.w;
    }
    __syncthreads();
#pragma unroll
    for (int i = 0; i < 4; ++i) {
        const int rr = tr + i * 16;
        ushort4 o;
        o.x = f2bf(tile[tc4 + 0][rr]);
        o.y = f2bf(tile[tc4 + 1][rr]);
        o.z = f2bf(tile[tc4 + 2][rr]);
        o.w = f2bf(tile[tc4 + 3][rr]);
        *(ushort4*)(dst + base + (size_t)(c0 + rr) * R + r0 + tc4) = o;
    }
}

// ---------------- grouped GEMM 1: h = gelu(Xg @ W1T[e]^T + b1[e]) -----------------
// A: Xg rows (pitch 1024 bf16), B: W1T[e][f][d] (pitch 1024), C: h (pitch 4096)
__global__ __launch_bounds__(256) void ffn1_kernel(
    const u16* __restrict__ Xg, const u16* __restrict__ W1T, const float* __restrict__ b1,
    u16* __restrict__ h, const int* __restrict__ offs, const int* __restrict__ counts) {
    const int e = blockIdx.x >> 10;
    const int rem = blockIdx.x & 1023;
    const int tm = rem >> 5, tn = rem & 31;
    const int cnt = counts[e];
    if (tm * 128 >= cnt) return;
    const int pbase = offs[e] + tm * 128;
    const int pend = offs[e] + cnt;
    const int fbase = tn * 128;
    const size_t wbase = (size_t)e * DFF * DMODEL;

    __shared__ __align__(16) u16 As[128 * 64];
    __shared__ __align__(16) u16 Bs[128 * 64];

    const int tid = threadIdx.x;
    const int lane = tid & 63, wid = tid >> 6;
    const int wm = (wid >> 1) * 64, wn = (wid & 1) * 64;
    const int fr = lane & 15, fg = lane >> 4;

    f32x4 acc[4][4];
#pragma unroll
    for (int a = 0; a < 4; ++a)
#pragma unroll
        for (int b = 0; b < 4; ++b) acc[a][b] = (f32x4){0.f, 0.f, 0.f, 0.f};

    for (int ks = 0; ks < DMODEL; ks += 64) {
        uint4 av[4], bv[4];
#pragma unroll
        for (int i = 0; i < 4; ++i) {
            const int c = tid + 256 * i;
            const int row = c >> 3, col = (c & 7) * 8;
            av[i] = *(const uint4*)(Xg + (size_t)(pbase + row) * DMODEL + ks + col);
            bv[i] = *(const uint4*)(W1T + wbase + (size_t)(fbase + row) * DMODEL + ks + col);
        }
        __syncthreads();
#pragma unroll
        for (int i = 0; i < 4; ++i) {
            const int c = tid + 256 * i;
            *(uint4*)(&As[c * 8]) = av[i];
            *(uint4*)(&Bs[c * 8]) = bv[i];
        }
        __syncthreads();
#pragma unroll
        for (int kc = 0; kc < 2; ++kc) {
            bf16x8 a[4], b[4];
#pragma unroll
            for (int i = 0; i < 4; ++i)
                a[i] = *(const bf16x8*)(&As[(wm + i * 16 + fr) * 64 + kc * 32 + fg * 8]);
#pragma unroll
            for (int i = 0; i < 4; ++i)
                b[i] = *(const bf16x8*)(&Bs[(wn + i * 16 + fr) * 64 + kc * 32 + fg * 8]);
#pragma unroll
            for (int am = 0; am < 4; ++am)
#pragma unroll
                for (int bn = 0; bn < 4; ++bn)
                    acc[am][bn] = __builtin_amdgcn_mfma_f32_16x16x32_bf16(
                        a[am], b[bn], acc[am][bn], 0, 0, 0);
        }
        __syncthreads();
    }
#pragma unroll
    for (int am = 0; am < 4; ++am) {
#pragma unroll
        for (int r = 0; r < 4; ++r) {
            const int p = pbase + wm + am * 16 + fg * 4 + r;
            if (p >= pend) continue;
#pragma unroll
            for (int bn = 0; bn < 4; ++bn) {
                const int f = fbase + wn + bn * 16 + fr;
                const float v = acc[am][bn][r] + b1[e * DFF + f];
                const float g = 0.5f * v * (1.f + erff(v * 0.70710678118654752f));
                h[(size_t)p * DFF + f] = f2bf(g);
            }
        }
    }
}

// ---------------- grouped GEMM 2: out[t] += gate * (h @ W2T[e]^T + b2[e]) --------
// A: h rows (pitch 4096 bf16), B: W2T[e][d][f] (pitch 4096), scatter to out
__global__ __launch_bounds__(256) void ffn2_kernel(
    const u16* __restrict__ h, const u16* __restrict__ W2T, const float* __restrict__ b2,
    const int* __restrict__ rowtoken, const float* __restrict__ rowgate,
    float* __restrict__ out, const int* __restrict__ offs, const int* __restrict__ counts) {
    const int e = blockIdx.x >> 8;
    const int rem = blockIdx.x & 255;
    const int tm = rem >> 3, tn = rem & 7;
    const int cnt = counts[e];
    if (tm * 128 >= cnt) return;
    const int pbase = offs[e] + tm * 128;
    const int pend = offs[e] + cnt;
    const int dbase = tn * 128;
    const size_t wbase = (size_t)e * DMODEL * DFF;

    __shared__ __align__(16) u16 As[128 * 64];
    __shared__ __align__(16) u16 Bs[128 * 64];

    const int tid = threadIdx.x;
    const int lane = tid & 63, wid = tid >> 6;
    const int wm = (wid >> 1) * 64, wn = (wid & 1) * 64;
    const int fr = lane & 15, fg = lane >> 4;

    f32x4 acc[4][4];
#pragma unroll
    for (int a = 0; a < 4; ++a)
#pragma unroll
        for (int b = 0; b < 4; ++b) acc[a][b] = (f32x4){0.f, 0.f, 0.f, 0.f};

    for (int ks = 0; ks < DFF; ks += 64) {
        uint4 av[4], bv[4];
#pragma unroll
        for (int i = 0; i < 4; ++i) {
            const int c = tid + 256 * i;
            const int row = c >> 3, col = (c & 7) * 8;
            av[i] = *(const uint4*)(h + (size_t)(pbase + row) * DFF + ks + col);
            bv[i] = *(const uint4*)(W2T + wbase + (size_t)(dbase + row) * DFF + ks + col);
        }
        __syncthreads();
#pragma unroll
        for (int i = 0; i < 4; ++i) {
            const int c = tid + 256 * i;
            *(uint4*)(&As[c * 8]) = av[i];
            *(uint4*)(&Bs[c * 8]) = bv[i];
        }
        __syncthreads();
#pragma unroll
        for (int kc = 0; kc < 2; ++kc) {
            bf16x8 a[4], b[4];
#pragma unroll
            for (int i = 0; i < 4; ++i)
                a[i] = *(const bf16x8*)(&As[(wm + i * 16 + fr) * 64 + kc * 32 + fg * 8]);
#pragma unroll
            for (int i = 0; i < 4; ++i)
                b[i] = *(const bf16x8*)(&Bs[(wn + i * 16 + fr) * 64 + kc * 32 + fg * 8]);
#pragma unroll
            for (int am = 0; am < 4; ++am)
#pragma unroll
                for (int bn = 0; bn < 4; ++bn)
                    acc[am][bn] = __builtin_amdgcn_mfma_f32_16x16x32_bf16(
                        a[am], b[bn], acc[am][bn], 0, 0, 0);
        }
        __syncthreads();
    }
#pragma unroll
    for (int am = 0; am < 4; ++am) {
#pragma unroll
        for (int r = 0; r < 4; ++r) {
            const int p = pbase + wm + am * 16 + fg * 4 + r;
            if (p >= pend) continue;
            const int t = rowtoken[p];
            const float g = rowgate[p];
#pragma unroll
            for (int bn = 0; bn < 4; ++bn) {
                const int d = dbase + wn + bn * 16 + fr;
                const float v = acc[am][bn][r] + b2[e * DMODEL + d];
                atomicAdd(&out[(size_t)t * DMODEL + d], g * v);
            }
        }
    }
}

extern "C" void kernel_launch(void* const* d_in, const int* in_sizes, int n_in,
                              void* d_out, int out_size, void* d_ws, size_t ws_size,
                              hipStream_t stream) {
    const float* x  = (const float*)d_in[0];
    const float* Wr = (const float*)d_in[1];
    const float* br = (const float*)d_in[2];
    const float* W1 = (const float*)d_in[3];
    const float* b1 = (const float*)d_in[4];
    const float* W2 = (const float*)d_in[5];
    const float* b2 = (const float*)d_in[6];
    float* out = (float*)d_out;

    // workspace carve
    char* w = (char*)d_ws;
    int*   counts   = (int*)(w + 0);
    int*   cursor   = (int*)(w + 32);
    int*   offs     = (int*)(w + 64);
    int*   top_idx  = (int*)(w + 256);
    float* gates    = (float*)(w + 256 + 32768);
    int*   rowtoken = (int*)(w + 256 + 65536);
    float* rowgate  = (float*)(w + 256 + 98304);
    u16*   Xg       = (u16*)(w + 256 + 131072);
    u16*   hbuf     = Xg + (size_t)ROWS_PAD * DMODEL;
    u16*   W1T      = hbuf + (size_t)ROWS_PAD * DFF;
    u16*   W2T      = W1T + (size_t)NEXP * DFF * DMODEL;
    const size_t need = (size_t)(256 + 131072)
        + (size_t)ROWS_PAD * DMODEL * 2 + (size_t)ROWS_PAD * DFF * 2
        + (size_t)NEXP * DFF * DMODEL * 4;
    if (ws_size < need) return;  // fail loudly (absmax) rather than corrupt memory

    hipMemsetAsync(d_out, 0, (size_t)out_size * sizeof(float), stream);
    hipMemsetAsync(d_ws, 0, 64, stream);  // counts + cursor

    // weight transpose/convert: W1 [e][1024][4096] -> W1T [e][4096][1024]
    transpose_convert_kernel<<<dim3(64, 16, 8), 256, 0, stream>>>(W1, W1T, DMODEL, DFF);
    // W2 [e][4096][1024] -> W2T [e][1024][4096]
    transpose_convert_kernel<<<dim3(16, 64, 8), 256, 0, stream>>>(W2, W2T, DFF, DMODEL);

    router_kernel<<<T_TOK, 64, 0, stream>>>(x, Wr, br, top_idx, gates, counts);
    scan_kernel<<<1, 64, 0, stream>>>(counts, offs, cursor);
    fill_kernel<<<16, 256, 0, stream>>>(top_idx, gates, cursor, rowtoken, rowgate);
    gather_kernel<<<ROWS_TOT, 256, 0, stream>>>(x, rowtoken, Xg);

    // ffn1: grid = 8 experts x 32 m-tiles x 32 n-tiles
    ffn1_kernel<<<8192, 256, 0, stream>>>(Xg, W1T, b1, hbuf, offs, counts);
    // ffn2: grid = 8 experts x 32 m-tiles x 8 n-tiles
    ffn2_kernel<<<2048, 256, 0, stream>>>(hbuf, W2T, b2, rowtoken, rowgate, out, offs, counts);
}

// Round 2
// 605.970 us; speedup vs baseline: 2.0401x; 2.0401x over previous
//
#include <hip/hip_runtime.h>
#include <hip/hip_bf16.h>

#define T_TOK 4096
#define DMODEL 1024
#define DFF 4096
#define NEXP 8
#define ROWS_TOT 8192      // T_TOK * TOPK, fixed
#define ROWS_PAD 8320      // + 128 pad rows for tile overrun

typedef __bf16 bf16x8 __attribute__((ext_vector_type(8)));
typedef float f32x4 __attribute__((ext_vector_type(4)));
typedef unsigned short u16;

__device__ __forceinline__ u16 f2bf(float f) {
    __hip_bfloat16 b = __float2bfloat16(f);
    return __builtin_bit_cast(u16, b);
}
__device__ __forceinline__ float bf2f(u16 u) {
    unsigned v = (unsigned)u << 16;
    return __builtin_bit_cast(float, v);
}

// ---------------- router: logits, softmax-top2 gates, expert histogram ----------
__global__ void router_kernel(const float* __restrict__ x, const float* __restrict__ Wr,
                              const float* __restrict__ br, int* __restrict__ top_idx,
                              float* __restrict__ gates, int* __restrict__ counts) {
    const int t = blockIdx.x;
    const int lane = threadIdx.x;
    float part[8];
#pragma unroll
    for (int e = 0; e < 8; ++e) part[e] = 0.f;
#pragma unroll
    for (int j = 0; j < 4; ++j) {
        const int d0 = j * 256 + lane * 4;
        const float4 xv = *(const float4*)(x + (size_t)t * DMODEL + d0);
        const float xs[4] = {xv.x, xv.y, xv.z, xv.w};
#pragma unroll
        for (int i = 0; i < 4; ++i) {
            const float4 w0 = *(const float4*)(Wr + (d0 + i) * 8);
            const float4 w1 = *(const float4*)(Wr + (d0 + i) * 8 + 4);
            part[0] += xs[i] * w0.x; part[1] += xs[i] * w0.y;
            part[2] += xs[i] * w0.z; part[3] += xs[i] * w0.w;
            part[4] += xs[i] * w1.x; part[5] += xs[i] * w1.y;
            part[6] += xs[i] * w1.z; part[7] += xs[i] * w1.w;
        }
    }
#pragma unroll
    for (int m = 32; m > 0; m >>= 1)
#pragma unroll
        for (int e = 0; e < 8; ++e) part[e] += __shfl_xor(part[e], m, 64);
    if (lane == 0) {
        float l[8];
#pragma unroll
        for (int e = 0; e < 8; ++e) l[e] = part[e] + br[e];
        int i1 = 0;
#pragma unroll
        for (int e = 1; e < 8; ++e) if (l[e] > l[i1]) i1 = e;   // first-index tiebreak
        int i2 = (i1 == 0) ? 1 : 0;
#pragma unroll
        for (int e = 0; e < 8; ++e) if (e != i1 && l[e] > l[i2]) i2 = e;
        // gates = softmax over {l[i1], l[i2]} (== topk(softmax)/sum(topk))
        const float e2 = expf(l[i2] - l[i1]);
        const float inv = 1.f / (1.f + e2);
        top_idx[t * 2 + 0] = i1;  gates[t * 2 + 0] = inv;
        top_idx[t * 2 + 1] = i2;  gates[t * 2 + 1] = e2 * inv;
        atomicAdd(&counts[i1], 1);
        atomicAdd(&counts[i2], 1);
    }
}

// ---------------- exclusive scan over 8 counts -----------------------------------
__global__ void scan_kernel(const int* __restrict__ counts, int* __restrict__ offs,
                            int* __restrict__ cursor) {
    if (threadIdx.x == 0) {
        int s = 0;
        for (int e = 0; e < 8; ++e) { offs[e] = s; cursor[e] = s; s += counts[e]; }
        offs[8] = s;
    }
}

// ---------------- fill sorted row lists + inverse map ----------------------------
__global__ void fill_kernel(const int* __restrict__ top_idx,
                            int* __restrict__ cursor, int* __restrict__ rowtoken,
                            int* __restrict__ slotof) {
    const int t = blockIdx.x * 256 + threadIdx.x;
    if (t >= T_TOK) return;
#pragma unroll
    for (int k = 0; k < 2; ++k) {
        const int e = top_idx[t * 2 + k];
        const int p = atomicAdd(&cursor[e], 1);
        rowtoken[p] = t;
        slotof[t * 2 + k] = p;
    }
}

// ---------------- gather x rows (fp32 -> bf16) into sorted order -----------------
__global__ void gather_kernel(const float* __restrict__ x, const int* __restrict__ rowtoken,
                              u16* __restrict__ Xg) {
    const int p = blockIdx.x;
    const int t = rowtoken[p];
    const int d = threadIdx.x * 4;
    const float4 v = *(const float4*)(x + (size_t)t * DMODEL + d);
    ushort4 o;
    o.x = f2bf(v.x); o.y = f2bf(v.y); o.z = f2bf(v.z); o.w = f2bf(v.w);
    *(ushort4*)(Xg + (size_t)p * DMODEL + d) = o;
}

// ---------------- transpose + fp32->bf16 weight conversion -----------------------
// src [batch][R][C] f32 -> dst [batch][C][R] bf16
__global__ __launch_bounds__(256) void transpose_convert_kernel(
    const float* __restrict__ src, u16* __restrict__ dst, int R, int C) {
    __shared__ float tile[64][65];
    const size_t base = (size_t)blockIdx.z * R * C;
    const int r0 = blockIdx.y * 64, c0 = blockIdx.x * 64;
    const int tr = threadIdx.x >> 4;
    const int tc4 = (threadIdx.x & 15) * 4;
#pragma unroll
    for (int i = 0; i < 4; ++i) {
        const int r = tr + i * 16;
        const float4 v = *(const float4*)(src + base + (size_t)(r0 + r) * C + c0 + tc4);
        tile[r][tc4 + 0] = v.x; tile[r][tc4 + 1] = v.y;
        tile[r][tc4 + 2] = v.z; tile[r][tc4 + 3] = v.w;
    }
    __syncthreads();
#pragma unroll
    for (int i = 0; i < 4; ++i) {
        const int rr = tr + i * 16;
        ushort4 o;
        o.x = f2bf(tile[tc4 + 0][rr]);
        o.y = f2bf(tile[tc4 + 1][rr]);
        o.z = f2bf(tile[tc4 + 2][rr]);
        o.w = f2bf(tile[tc4 + 3][rr]);
        *(ushort4*)(dst + base + (size_t)(c0 + rr) * R + r0 + tc4) = o;
    }
}

// ---------------- grouped GEMM 1: h = gelu(Xg @ W1T[e]^T + b1[e]) -----------------
// A: Xg rows (pitch 1024 bf16), B: W1T[e][f][d] (pitch 1024), C: h (pitch 4096)
__global__ __launch_bounds__(256) void ffn1_kernel(
    const u16* __restrict__ Xg, const u16* __restrict__ W1T, const float* __restrict__ b1,
    u16* __restrict__ h, const int* __restrict__ offs, const int* __restrict__ counts) {
    const int e = blockIdx.x >> 10;
    const int rem = blockIdx.x & 1023;
    const int tm = rem >> 5, tn = rem & 31;
    const int cnt = counts[e];
    if (tm * 128 >= cnt) return;
    const int pbase = offs[e] + tm * 128;
    const int pend = offs[e] + cnt;
    const int fbase = tn * 128;
    const size_t wbase = (size_t)e * DFF * DMODEL;

    __shared__ __align__(16) u16 As[128 * 64];
    __shared__ __align__(16) u16 Bs[128 * 64];

    const int tid = threadIdx.x;
    const int lane = tid & 63, wid = tid >> 6;
    const int wm = (wid >> 1) * 64, wn = (wid & 1) * 64;
    const int fr = lane & 15, fg = lane >> 4;

    // per-lane global row/col for staging (LDS dest is linear: byte c*16)
    const int srow = (tid >> 3), scol = (tid & 7) * 8;   // c = tid + 256*i -> row = srow + 32*i

    f32x4 acc[4][4];
#pragma unroll
    for (int a = 0; a < 4; ++a)
#pragma unroll
        for (int b = 0; b < 4; ++b) acc[a][b] = (f32x4){0.f, 0.f, 0.f, 0.f};

    for (int ks = 0; ks < DMODEL; ks += 64) {
#pragma unroll
        for (int i = 0; i < 4; ++i) {
            const int row = srow + 32 * i;
            __builtin_amdgcn_global_load_lds(
                (const __attribute__((address_space(1))) void*)
                    (Xg + (size_t)(pbase + row) * DMODEL + ks + scol),
                (__attribute__((address_space(3))) void*)(As + (size_t)(wid * 64 + i * 256) * 8),
                16, 0, 0);
            __builtin_amdgcn_global_load_lds(
                (const __attribute__((address_space(1))) void*)
                    (W1T + wbase + (size_t)(fbase + row) * DMODEL + ks + scol),
                (__attribute__((address_space(3))) void*)(Bs + (size_t)(wid * 64 + i * 256) * 8),
                16, 0, 0);
        }
        __syncthreads();
#pragma unroll
        for (int kc = 0; kc < 2; ++kc) {
            bf16x8 a[4], b[4];
#pragma unroll
            for (int i = 0; i < 4; ++i)
                a[i] = *(const bf16x8*)(&As[(wm + i * 16 + fr) * 64 + kc * 32 + fg * 8]);
#pragma unroll
            for (int i = 0; i < 4; ++i)
                b[i] = *(const bf16x8*)(&Bs[(wn + i * 16 + fr) * 64 + kc * 32 + fg * 8]);
#pragma unroll
            for (int am = 0; am < 4; ++am)
#pragma unroll
                for (int bn = 0; bn < 4; ++bn)
                    acc[am][bn] = __builtin_amdgcn_mfma_f32_16x16x32_bf16(
                        a[am], b[bn], acc[am][bn], 0, 0, 0);
        }
        __syncthreads();
    }
#pragma unroll
    for (int am = 0; am < 4; ++am) {
#pragma unroll
        for (int r = 0; r < 4; ++r) {
            const int p = pbase + wm + am * 16 + fg * 4 + r;
            if (p >= pend) continue;
#pragma unroll
            for (int bn = 0; bn < 4; ++bn) {
                const int f = fbase + wn + bn * 16 + fr;
                const float v = acc[am][bn][r] + b1[e * DFF + f];
                const float g = 0.5f * v * (1.f + erff(v * 0.70710678118654752f));
                h[(size_t)p * DFF + f] = f2bf(g);
            }
        }
    }
}

// ---------------- grouped GEMM 2: ybuf[p] = h[p] @ W2T[e]^T (no bias, no gate) ---
// A: h rows (pitch 4096 bf16), B: W2T[e][d][f] (pitch 4096), C: ybuf bf16 (pitch 1024)
__global__ __launch_bounds__(256) void ffn2_kernel(
    const u16* __restrict__ h, const u16* __restrict__ W2T,
    u16* __restrict__ ybuf, const int* __restrict__ offs, const int* __restrict__ counts) {
    const int e = blockIdx.x >> 8;
    const int rem = blockIdx.x & 255;
    const int tm = rem >> 3, tn = rem & 7;
    const int cnt = counts[e];
    if (tm * 128 >= cnt) return;
    const int pbase = offs[e] + tm * 128;
    const int pend = offs[e] + cnt;
    const int dbase = tn * 128;
    const size_t wbase = (size_t)e * DMODEL * DFF;

    __shared__ __align__(16) u16 As[128 * 64];
    __shared__ __align__(16) u16 Bs[128 * 64];

    const int tid = threadIdx.x;
    const int lane = tid & 63, wid = tid >> 6;
    const int wm = (wid >> 1) * 64, wn = (wid & 1) * 64;
    const int fr = lane & 15, fg = lane >> 4;

    const int srow = (tid >> 3), scol = (tid & 7) * 8;

    f32x4 acc[4][4];
#pragma unroll
    for (int a = 0; a < 4; ++a)
#pragma unroll
        for (int b = 0; b < 4; ++b) acc[a][b] = (f32x4){0.f, 0.f, 0.f, 0.f};

    for (int ks = 0; ks < DFF; ks += 64) {
#pragma unroll
        for (int i = 0; i < 4; ++i) {
            const int row = srow + 32 * i;
            __builtin_amdgcn_global_load_lds(
                (const __attribute__((address_space(1))) void*)
                    (h + (size_t)(pbase + row) * DFF + ks + scol),
                (__attribute__((address_space(3))) void*)(As + (size_t)(wid * 64 + i * 256) * 8),
                16, 0, 0);
            __builtin_amdgcn_global_load_lds(
                (const __attribute__((address_space(1))) void*)
                    (W2T + wbase + (size_t)(dbase + row) * DFF + ks + scol),
                (__attribute__((address_space(3))) void*)(Bs + (size_t)(wid * 64 + i * 256) * 8),
                16, 0, 0);
        }
        __syncthreads();
#pragma unroll
        for (int kc = 0; kc < 2; ++kc) {
            bf16x8 a[4], b[4];
#pragma unroll
            for (int i = 0; i < 4; ++i)
                a[i] = *(const bf16x8*)(&As[(wm + i * 16 + fr) * 64 + kc * 32 + fg * 8]);
#pragma unroll
            for (int i = 0; i < 4; ++i)
                b[i] = *(const bf16x8*)(&Bs[(wn + i * 16 + fr) * 64 + kc * 32 + fg * 8]);
#pragma unroll
            for (int am = 0; am < 4; ++am)
#pragma unroll
                for (int bn = 0; bn < 4; ++bn)
                    acc[am][bn] = __builtin_amdgcn_mfma_f32_16x16x32_bf16(
                        a[am], b[bn], acc[am][bn], 0, 0, 0);
        }
        __syncthreads();
    }
#pragma unroll
    for (int am = 0; am < 4; ++am) {
#pragma unroll
        for (int r = 0; r < 4; ++r) {
            const int p = pbase + wm + am * 16 + fg * 4 + r;
            if (p >= pend) continue;
#pragma unroll
            for (int bn = 0; bn < 4; ++bn) {
                const int d = dbase + wn + bn * 16 + fr;
                ybuf[(size_t)p * DMODEL + d] = f2bf(acc[am][bn][r]);
            }
        }
    }
}

// ---------------- combine: out[t] = sum_k g_k * (y[p_k] + b2[e_k]) ---------------
__global__ void combine_kernel(const u16* __restrict__ ybuf, const float* __restrict__ b2,
                               const int* __restrict__ top_idx, const float* __restrict__ gates,
                               const int* __restrict__ slotof, float* __restrict__ out) {
    const int t = blockIdx.x;
    const int d = threadIdx.x * 4;
    const int e0 = top_idx[t * 2 + 0], e1 = top_idx[t * 2 + 1];
    const float g0 = gates[t * 2 + 0], g1 = gates[t * 2 + 1];
    const int p0 = slotof[t * 2 + 0], p1 = slotof[t * 2 + 1];
    const ushort4 ya = *(const ushort4*)(ybuf + (size_t)p0 * DMODEL + d);
    const ushort4 yb = *(const ushort4*)(ybuf + (size_t)p1 * DMODEL + d);
    const float4 ba = *(const float4*)(b2 + e0 * DMODEL + d);
    const float4 bb = *(const float4*)(b2 + e1 * DMODEL + d);
    float4 o;
    o.x = g0 * (bf2f(ya.x) + ba.x) + g1 * (bf2f(yb.x) + bb.x);
    o.y = g0 * (bf2f(ya.y) + ba.y) + g1 * (bf2f(yb.y) + bb.y);
    o.z = g0 * (bf2f(ya.z) + ba.z) + g1 * (bf2f(yb.z) + bb.z);
    o.w = g0 * (bf2f(ya.w) + ba.w) + g1 * (bf2f(yb.w) + bb.w);
    *(float4*)(out + (size_t)t * DMODEL + d) = o;
}

extern "C" void kernel_launch(void* const* d_in, const int* in_sizes, int n_in,
                              void* d_out, int out_size, void* d_ws, size_t ws_size,
                              hipStream_t stream) {
    const float* x  = (const float*)d_in[0];
    const float* Wr = (const float*)d_in[1];
    const float* br = (const float*)d_in[2];
    const float* W1 = (const float*)d_in[3];
    const float* b1 = (const float*)d_in[4];
    const float* W2 = (const float*)d_in[5];
    const float* b2 = (const float*)d_in[6];
    float* out = (float*)d_out;

    // workspace carve (all 16B aligned)
    char* w = (char*)d_ws;
    int*   counts   = (int*)(w + 0);          // 32 B
    int*   cursor   = (int*)(w + 32);         // 32 B
    int*   offs     = (int*)(w + 64);         // 64 B
    int*   top_idx  = (int*)(w + 1024);                   // 32 KB
    float* gates    = (float*)(w + 1024 + 32768);         // 32 KB
    int*   rowtoken = (int*)(w + 1024 + 65536);           // 40 KB reserved
    int*   slotof   = (int*)(w + 1024 + 65536 + 40960);   // 32 KB
    u16*   Xg       = (u16*)(w + 1024 + 65536 + 40960 + 32768);  // 17 MB; ybuf aliases this
    u16*   hbuf     = Xg + (size_t)ROWS_PAD * DMODEL;            // 68 MB
    u16*   W1T      = hbuf + (size_t)ROWS_PAD * DFF;             // 64 MB
    u16*   W2T      = W1T + (size_t)NEXP * DFF * DMODEL;         // 64 MB
    u16*   ybuf     = Xg;   // Xg dead after ffn1; same size [ROWS_PAD][DMODEL]
    const size_t need = (size_t)(1024 + 65536 + 40960 + 32768)
        + (size_t)ROWS_PAD * DMODEL * 2 + (size_t)ROWS_PAD * DFF * 2
        + (size_t)NEXP * DFF * DMODEL * 4;
    if (ws_size < need) return;  // fail loudly (absmax) rather than corrupt memory

    hipMemsetAsync(d_ws, 0, 64, stream);  // counts + cursor

    // weight transpose/convert: W1 [e][1024][4096] -> W1T [e][4096][1024]
    transpose_convert_kernel<<<dim3(64, 16, 8), 256, 0, stream>>>(W1, W1T, DMODEL, DFF);
    // W2 [e][4096][1024] -> W2T [e][1024][4096]
    transpose_convert_kernel<<<dim3(16, 64, 8), 256, 0, stream>>>(W2, W2T, DFF, DMODEL);

    router_kernel<<<T_TOK, 64, 0, stream>>>(x, Wr, br, top_idx, gates, counts);
    scan_kernel<<<1, 64, 0, stream>>>(counts, offs, cursor);
    fill_kernel<<<16, 256, 0, stream>>>(top_idx, cursor, rowtoken, slotof);
    gather_kernel<<<ROWS_TOT, 256, 0, stream>>>(x, rowtoken, Xg);

    // ffn1: grid = 8 experts x 32 m-tiles x 32 n-tiles
    ffn1_kernel<<<8192, 256, 0, stream>>>(Xg, W1T, b1, hbuf, offs, counts);
    // ffn2: grid = 8 experts x 32 m-tiles x 8 n-tiles
    ffn2_kernel<<<2048, 256, 0, stream>>>(hbuf, W2T, ybuf, offs, counts);
    // combine: one block per token
    combine_kernel<<<T_TOK, 256, 0, stream>>>(ybuf, b2, top_idx, gates, slotof, out);
}